// Round 12
// baseline (245.772 us; speedup 1.0000x reference)
//
#include <hip/hip_runtime.h>
#include <math.h>

// ---------------------------------------------------------------------------
// GCN: h1 = relu(Agg(x@W1)+b1); h2 = relu(Agg(h1@W2)+b2); out = sigmoid(h2@Wfc+bfc)
// Agg(xl)[dst] = dinv[dst] * ( sum_{src->dst} xl_s[src] + xl_s[dst] )
//   where xl_s[n] = (x@W)[n] * dinv[n]   (source-side norm folded into GEMM)
// R2-R9: scan / dinv-fold / counting-sort CSR (no global atomics).
// R10: MFMA GEMMs. R11: branch-free prefetched 32-bit gather (VALUBusy 74%).
// R12: fold-free agg — 8 nodes/wave (slot=lane>>3 owns a node, octet=lane&7
//      owns 8 feats). Kills the 36-VALU/node shuffle fold + separate self
//      path; self = virtual edge at it==deg; 1KB contiguous stores.
//      Cost: loop runs to wave-max(deg+1) (clamped lanes are L1-hot + masked).
// ---------------------------------------------------------------------------

typedef __attribute__((ext_vector_type(8))) short bf16x8;
typedef __attribute__((ext_vector_type(4))) float f32x4;
typedef __attribute__((ext_vector_type(2))) float f32x2;

#define CHUNKS 1024

__device__ __forceinline__ unsigned short f2bf(float f) {
    unsigned u = __float_as_uint(f);
    u += 0x7FFFu + ((u >> 16) & 1u);   // round-to-nearest-even
    return (unsigned short)(u >> 16);
}
__device__ __forceinline__ unsigned packbf(float a, float b) {
    return (unsigned)f2bf(a) | ((unsigned)f2bf(b) << 16);
}
// accumulate 8 bf16 (one uint4) into 4 packed f32x2 accumulators
__device__ __forceinline__ void upadd2(uint4 g, f32x2* a) {
    a[0] += (f32x2){__uint_as_float(g.x << 16), __uint_as_float(g.x & 0xFFFF0000u)};
    a[1] += (f32x2){__uint_as_float(g.y << 16), __uint_as_float(g.y & 0xFFFF0000u)};
    a[2] += (f32x2){__uint_as_float(g.z << 16), __uint_as_float(g.z & 0xFFFF0000u)};
    a[3] += (f32x2){__uint_as_float(g.w << 16), __uint_as_float(g.w & 0xFFFF0000u)};
}

// ---- CSR build: bucketed counting sort (no global atomics) ----------------
__global__ __launch_bounds__(256) void k_hist(const int* __restrict__ col, int E,
                                              int NBUK, int CH,
                                              int* __restrict__ hist_g) {
    __shared__ int h[256];
    for (int i = threadIdx.x; i < NBUK; i += 256) h[i] = 0;
    __syncthreads();
    int base = blockIdx.x * CH, hi = min(base + CH, E);
    for (int e = base + (int)threadIdx.x; e < hi; e += 256)
        atomicAdd(&h[col[e] >> 9], 1);
    __syncthreads();
    for (int i = threadIdx.x; i < NBUK; i += 256)
        hist_g[blockIdx.x * NBUK + i] = h[i];
}

__global__ __launch_bounds__(256) void k_colscan(const int* __restrict__ hist_g, int NBUK,
                                                 int* __restrict__ histOff,
                                                 int* __restrict__ bucketTotal) {
    __shared__ int s[256];
    const int b = blockIdx.x, t = threadIdx.x;
    int v[4], sum = 0;
#pragma unroll
    for (int j = 0; j < 4; ++j) {
        v[j] = hist_g[(t * 4 + j) * NBUK + b];
        sum += v[j];
    }
    s[t] = sum;
    __syncthreads();
    for (int off = 1; off < 256; off <<= 1) {
        int u = (t >= off) ? s[t - off] : 0;
        __syncthreads();
        s[t] += u;
        __syncthreads();
    }
    int run = s[t] - sum;
#pragma unroll
    for (int j = 0; j < 4; ++j) {
        histOff[b * CHUNKS + t * 4 + j] = run;
        run += v[j];
    }
    if (t == 255) bucketTotal[b] = run;
}

__global__ __launch_bounds__(256) void k_scan_tot(const int* __restrict__ bucketTotal,
                                                  int NBUK, int E, int N,
                                                  int* __restrict__ bucketBase,
                                                  int* __restrict__ row_off) {
    __shared__ int s[256];
    int t = threadIdx.x;
    int v = (t < NBUK) ? bucketTotal[t] : 0;
    s[t] = v;
    __syncthreads();
    for (int off = 1; off < 256; off <<= 1) {
        int u = (t >= off) ? s[t - off] : 0;
        __syncthreads();
        s[t] += u;
        __syncthreads();
    }
    if (t < NBUK) bucketBase[t] = s[t] - v;
    if (t == 0) row_off[N] = E;
}

__global__ __launch_bounds__(256) void k_scatter(const int* __restrict__ row,
                                                 const int* __restrict__ col, int E,
                                                 int NBUK, int CH,
                                                 const int* __restrict__ bucketBase,
                                                 const int* __restrict__ histOff,
                                                 unsigned* __restrict__ ebuf) {
    __shared__ int cur[256];
    for (int i = threadIdx.x; i < NBUK; i += 256)
        cur[i] = bucketBase[i] + histOff[i * CHUNKS + blockIdx.x];
    __syncthreads();
    int base = blockIdx.x * CH, hi = min(base + CH, E);
    for (int e = base + (int)threadIdx.x; e < hi; e += 256) {
        int d = col[e], src = row[e];
        int b = d >> 9;
        int pos = atomicAdd(&cur[b], 1);             // LDS atomic
        ebuf[pos] = ((unsigned)(d & 511) << 17) | (unsigned)src;
    }
}

__global__ __launch_bounds__(512) void k_bucket(const unsigned* __restrict__ ebuf,
                                                const int* __restrict__ bucketBase,
                                                const int* __restrict__ bucketTotal,
                                                int N,
                                                int* __restrict__ row_off,
                                                float* __restrict__ dinv,
                                                int* __restrict__ csr_src) {
    __shared__ int hc[512], of[512];
    const int bid = blockIdx.x, t = threadIdx.x;
    const int base = bucketBase[bid];
    const int cnt  = bucketTotal[bid];
    hc[t] = 0;
    __syncthreads();
    for (int i = t; i < cnt; i += 512)
        atomicAdd(&hc[ebuf[base + i] >> 17], 1);
    __syncthreads();
    int v = hc[t];
    of[t] = v;
    __syncthreads();
    for (int off = 1; off < 512; off <<= 1) {
        int u = (t >= off) ? of[t - off] : 0;
        __syncthreads();
        of[t] += u;
        __syncthreads();
    }
    int excl = of[t] - v;
    int node = bid * 512 + t;
    if (node < N) {
        row_off[node] = base + excl;
        dinv[node] = rsqrtf((float)(v + 1));   // +1 self loop
    }
    of[t] = excl;
    __syncthreads();
    for (int i = t; i < cnt; i += 512) {
        unsigned e = ebuf[base + i];
        int dl = (int)(e >> 17), src = (int)(e & 0x1FFFFu);
        int pos = atomicAdd(&of[dl], 1);       // LDS atomic
        csr_src[base + pos] = src;
    }
}

// ---- MFMA GEMM ------------------------------------------------------------
template <int K, bool BF16IN>
__global__ __launch_bounds__(256) void k_gemm_mfma(const void* __restrict__ xin,
                                                   const float* __restrict__ W,
                                                   const float* __restrict__ dinv,
                                                   unsigned short* __restrict__ out,
                                                   int N) {
    constexpr int KS = K + 8;
    __shared__ short sX[64 * KS];
    __shared__ short sW[64 * KS];
    const int tid = threadIdx.x;
    const int wv = tid >> 6, lane = tid & 63;
    const int q = lane >> 4, m = lane & 15;
    const int nb = blockIdx.x * 64;

    for (int i = tid; i < K * 64; i += 256) {
        int k = i >> 6, c = i & 63;
        sW[c * KS + k] = (short)f2bf(W[i]);
    }
    if (BF16IN) {
        const unsigned short* xb = (const unsigned short*)xin;
        for (int i = tid; i < 64 * (K / 8); i += 256) {
            int r = i / (K / 8), c8 = (i % (K / 8)) * 8;
            int node = nb + r;
            uint4 v = make_uint4(0u, 0u, 0u, 0u);
            if (node < N) v = *(const uint4*)(xb + (size_t)node * K + c8);
            *(uint4*)(&sX[r * KS + c8]) = v;
        }
    } else {
        const float* xf = (const float*)xin;
        for (int i = tid; i < 64 * (K / 8); i += 256) {
            int r = i / (K / 8), c8 = (i % (K / 8)) * 8;
            int node = nb + r;
            uint4 v = make_uint4(0u, 0u, 0u, 0u);
            if (node < N) {
                float4 lo = *(const float4*)(xf + (size_t)node * K + c8);
                float4 hi = *(const float4*)(xf + (size_t)node * K + c8 + 4);
                v.x = packbf(lo.x, lo.y);
                v.y = packbf(lo.z, lo.w);
                v.z = packbf(hi.x, hi.y);
                v.w = packbf(hi.z, hi.w);
            }
            *(uint4*)(&sX[r * KS + c8]) = v;
        }
    }
    __syncthreads();

    f32x4 acc[4] = {};
    const short* aRow = &sX[(wv * 16 + m) * KS + q * 8];
#pragma unroll
    for (int k0 = 0; k0 < K; k0 += 32) {
        bf16x8 a = *(const bf16x8*)(aRow + k0);
#pragma unroll
        for (int ft = 0; ft < 4; ++ft) {
            bf16x8 b = *(const bf16x8*)(&sW[(ft * 16 + m) * KS + k0 + q * 8]);
            acc[ft] = __builtin_amdgcn_mfma_f32_16x16x32_bf16(a, b, acc[ft], 0, 0, 0);
        }
    }
#pragma unroll
    for (int r = 0; r < 4; ++r) {
        int node = nb + wv * 16 + q * 4 + r;
        if (node < N) {
            float di = dinv[node];
#pragma unroll
            for (int ft = 0; ft < 4; ++ft)
                out[(size_t)node * 64 + ft * 16 + m] = f2bf(acc[ft][r] * di);
        }
    }
}

// ---- aggregation: 8 nodes per wave, fold-free -----------------------------
// slot s = lane>>3 owns node base+s; octet o = lane&7 owns feats [8o,8o+8).
// Slot's 8 lanes cooperatively load one 128B src row per iteration.
// Self-loop = virtual edge at it==deg. Loop runs to wave-max(deg+1);
// invalid iterations clamp to the node's own row (L1-hot) and are masked.
__global__ __launch_bounds__(256) void k_agg(const unsigned short* __restrict__ xl,
                                             const int* __restrict__ row_off,
                                             const int* __restrict__ csr_src,
                                             const float* __restrict__ dinv,
                                             const float* __restrict__ bias,
                                             unsigned short* __restrict__ out, int N) {
    const int wave = threadIdx.x >> 6, lane = threadIdx.x & 63;
    const int s = lane >> 3, o = lane & 7;
    int node = (blockIdx.x * 4 + wave) * 8 + s;
    const bool active = node < N;
    node = min(node, N - 1);
    const int beg = row_off[node];
    const int deg = row_off[node + 1] - beg;
    const int cnt = active ? deg + 1 : 0;
    int mx = cnt;                         // wave-max over the 8 slots
    mx = max(mx, __shfl_xor(mx, 8, 64));
    mx = max(mx, __shfl_xor(mx, 16, 64));
    mx = max(mx, __shfl_xor(mx, 32, 64));
    const char* xlb = (const char*)xl;
    const unsigned loff = (unsigned)(o << 4);
    f32x2 acc[4] = {};
    int idx = (0 < deg) ? csr_src[beg] : node;
    for (int it = 0; it < mx; ++it) {
        const int cur = idx;
        const bool valid = it < cnt;
        const int nit = it + 1;
        idx = (nit < deg) ? csr_src[beg + nit] : node;   // prefetch (self at it==deg)
        uint4 g = *(const uint4*)(xlb + (((unsigned)cur << 7) | loff));
        if (!valid) g = make_uint4(0u, 0u, 0u, 0u);
        upadd2(g, acc);
    }
    if (active) {
        float di = dinv[node];
        float4 blo = *(const float4*)(bias + o * 8);
        float4 bhi = *(const float4*)(bias + o * 8 + 4);
        uint4 r;
        r.x = packbf(fmaxf(acc[0].x * di + blo.x, 0.f), fmaxf(acc[0].y * di + blo.y, 0.f));
        r.y = packbf(fmaxf(acc[1].x * di + blo.z, 0.f), fmaxf(acc[1].y * di + blo.w, 0.f));
        r.z = packbf(fmaxf(acc[2].x * di + bhi.x, 0.f), fmaxf(acc[2].y * di + bhi.y, 0.f));
        r.w = packbf(fmaxf(acc[3].x * di + bhi.z, 0.f), fmaxf(acc[3].y * di + bhi.w, 0.f));
        *(uint4*)(out + (size_t)node * 64 + o * 8) = r;  // 1KB contiguous per wave
    }
}

// Layer-2 agg + final FC + sigmoid (octet fold: shfl_xor 1/2/4 within slot).
__global__ __launch_bounds__(256) void k_agg_fc(const unsigned short* __restrict__ xl,
                                                const int* __restrict__ row_off,
                                                const int* __restrict__ csr_src,
                                                const float* __restrict__ dinv,
                                                const float* __restrict__ bias,
                                                const float* __restrict__ Wfc,
                                                const float* __restrict__ bfc,
                                                float* __restrict__ out, int N) {
    const int wave = threadIdx.x >> 6, lane = threadIdx.x & 63;
    const int s = lane >> 3, o = lane & 7;
    int node = (blockIdx.x * 4 + wave) * 8 + s;
    const bool active = node < N;
    node = min(node, N - 1);
    const int beg = row_off[node];
    const int deg = row_off[node + 1] - beg;
    const int cnt = active ? deg + 1 : 0;
    int mx = cnt;
    mx = max(mx, __shfl_xor(mx, 8, 64));
    mx = max(mx, __shfl_xor(mx, 16, 64));
    mx = max(mx, __shfl_xor(mx, 32, 64));
    const char* xlb = (const char*)xl;
    const unsigned loff = (unsigned)(o << 4);
    f32x2 acc[4] = {};
    int idx = (0 < deg) ? csr_src[beg] : node;
    for (int it = 0; it < mx; ++it) {
        const int cur = idx;
        const bool valid = it < cnt;
        const int nit = it + 1;
        idx = (nit < deg) ? csr_src[beg + nit] : node;
        uint4 g = *(const uint4*)(xlb + (((unsigned)cur << 7) | loff));
        if (!valid) g = make_uint4(0u, 0u, 0u, 0u);
        upadd2(g, acc);
    }
    const float di = dinv[node];
    float4 blo = *(const float4*)(bias + o * 8);
    float4 bhi = *(const float4*)(bias + o * 8 + 4);
    float4 wlo = *(const float4*)(Wfc + o * 8);
    float4 whi = *(const float4*)(Wfc + o * 8 + 4);
    float v = 0.f;
    v += fmaxf(acc[0].x * di + blo.x, 0.f) * wlo.x;
    v += fmaxf(acc[0].y * di + blo.y, 0.f) * wlo.y;
    v += fmaxf(acc[1].x * di + blo.z, 0.f) * wlo.z;
    v += fmaxf(acc[1].y * di + blo.w, 0.f) * wlo.w;
    v += fmaxf(acc[2].x * di + bhi.x, 0.f) * whi.x;
    v += fmaxf(acc[2].y * di + bhi.y, 0.f) * whi.y;
    v += fmaxf(acc[3].x * di + bhi.z, 0.f) * whi.z;
    v += fmaxf(acc[3].y * di + bhi.w, 0.f) * whi.w;
    v += __shfl_xor(v, 1, 64);
    v += __shfl_xor(v, 2, 64);
    v += __shfl_xor(v, 4, 64);
    if (active && o == 0) out[node] = 1.f / (1.f + expf(-(v + bfc[0])));
}

extern "C" void kernel_launch(void* const* d_in, const int* in_sizes, int n_in,
                              void* d_out, int out_size, void* d_ws, size_t ws_size,
                              hipStream_t stream) {
    const float* x   = (const float*)d_in[0];
    const int*   ei  = (const int*)d_in[1];   // [2, E]: row then col
    const float* W1  = (const float*)d_in[2];
    const float* b1  = (const float*)d_in[3];
    const float* W2  = (const float*)d_in[4];
    const float* b2  = (const float*)d_in[5];
    const float* Wfc = (const float*)d_in[6];
    const float* bfc = (const float*)d_in[7];
    float* out = (float*)d_out;

    const int H = in_sizes[3];          // 64
    const int D = in_sizes[2] / H;      // 128
    const int N = in_sizes[0] / D;      // 100000
    const int E = in_sizes[1] / 2;      // 1600000
    const int* row = ei;
    const int* col = ei + E;
    const int NBUK = (N + 511) >> 9;    // 196 buckets of 512 nodes
    const int CH   = (E + CHUNKS - 1) / CHUNKS;

    // Workspace carve-up (256B aligned slices)
    char* p = (char*)d_ws;
    auto carve = [&](size_t bytes) {
        char* r = p;
        p += (bytes + 255) & ~(size_t)255;
        return (void*)r;
    };
    int*            hist_g      = (int*)carve((size_t)CHUNKS * 256 * 4);
    int*            histOff     = (int*)carve((size_t)256 * CHUNKS * 4);
    int*            bucketTotal = (int*)carve((size_t)256 * 4);
    int*            bucketBase  = (int*)carve((size_t)256 * 4);
    unsigned*       ebuf        = (unsigned*)carve((size_t)E * 4);
    int*            csr_src     = (int*)carve((size_t)E * 4);
    int*            row_off     = (int*)carve((size_t)(N + 1) * 4);
    float*          dinv        = (float*)carve((size_t)N * 4);
    unsigned short* bufXL       = (unsigned short*)carve((size_t)N * 64 * 2);
    unsigned short* bufH        = (unsigned short*)carve((size_t)N * 64 * 2);
    (void)ws_size;

    const int TB = 256;
    // 1. CSR build (bucketed counting sort; no global atomics)
    k_hist<<<CHUNKS, TB, 0, stream>>>(col, E, NBUK, CH, hist_g);
    k_colscan<<<NBUK, TB, 0, stream>>>(hist_g, NBUK, histOff, bucketTotal);
    k_scan_tot<<<1, TB, 0, stream>>>(bucketTotal, NBUK, E, N, bucketBase, row_off);
    k_scatter<<<CHUNKS, TB, 0, stream>>>(row, col, E, NBUK, CH, bucketBase, histOff, ebuf);
    k_bucket<<<NBUK, 512, 0, stream>>>(ebuf, bucketBase, bucketTotal, N,
                                       row_off, dinv, csr_src);

    int gemmGrid = (N + 63) / 64;       // 1563
    int aggGrid  = (N + 31) / 32;       // 3125 (8 nodes/wave x 4 waves)
    // 2. layer 1: xl = bf16((x@W1)*dinv) ; h1 = bf16(relu(dinv*Agg(xl)+b1))
    k_gemm_mfma<128, false><<<gemmGrid, TB, 0, stream>>>(x, W1, dinv, bufXL, N);
    k_agg<<<aggGrid, TB, 0, stream>>>(bufXL, row_off, csr_src, dinv, b1, bufH, N);
    // 3. layer 2: xl2 = bf16((h1@W2)*dinv) ; out = sigmoid(relu(dinv*Agg+b2)@Wfc+bfc)
    k_gemm_mfma<64, true><<<gemmGrid, TB, 0, stream>>>(bufH, W2, dinv, bufXL, N);
    k_agg_fc<<<aggGrid, TB, 0, stream>>>(bufXL, row_off, csr_src, dinv, b2, Wfc, bfc, out, N);
}

// Round 13
// 223.246 us; speedup vs baseline: 1.1009x; 1.1009x over previous
//
#include <hip/hip_runtime.h>
#include <math.h>

// ---------------------------------------------------------------------------
// GCN: h1 = relu(Agg(x@W1)+b1); h2 = relu(Agg(h1@W2)+b2); out = sigmoid(h2@Wfc+bfc)
// Agg(xl)[dst] = dinv[dst] * ( sum_{src->dst} xl_s[src] + xl_s[dst] )
//   where xl_s[n] = (x@W)[n] * dinv[n]   (source-side norm folded into GEMM)
// R2-R9: scan / dinv-fold / counting-sort CSR (no global atomics).
// R10: MFMA GEMMs. R11: branch-free prefetched 32-bit gather.
// R12: fold-free agg, 8 nodes/wave (VALU 74%->26% but neutral: latency-bound,
//      only ONE gather in flight per slot).
// R13: 2-way edge unroll per slot — two independent prefetch+gather chains,
//      two accumulator banks (restores R11's MLP inside R12's fold-free shape).
// ---------------------------------------------------------------------------

typedef __attribute__((ext_vector_type(8))) short bf16x8;
typedef __attribute__((ext_vector_type(4))) float f32x4;
typedef __attribute__((ext_vector_type(2))) float f32x2;

#define CHUNKS 1024

__device__ __forceinline__ unsigned short f2bf(float f) {
    unsigned u = __float_as_uint(f);
    u += 0x7FFFu + ((u >> 16) & 1u);   // round-to-nearest-even
    return (unsigned short)(u >> 16);
}
__device__ __forceinline__ unsigned packbf(float a, float b) {
    return (unsigned)f2bf(a) | ((unsigned)f2bf(b) << 16);
}
// accumulate 8 bf16 (one uint4) into 4 packed f32x2 accumulators
__device__ __forceinline__ void upadd2(uint4 g, f32x2* a) {
    a[0] += (f32x2){__uint_as_float(g.x << 16), __uint_as_float(g.x & 0xFFFF0000u)};
    a[1] += (f32x2){__uint_as_float(g.y << 16), __uint_as_float(g.y & 0xFFFF0000u)};
    a[2] += (f32x2){__uint_as_float(g.z << 16), __uint_as_float(g.z & 0xFFFF0000u)};
    a[3] += (f32x2){__uint_as_float(g.w << 16), __uint_as_float(g.w & 0xFFFF0000u)};
}

// ---- CSR build: bucketed counting sort (no global atomics) ----------------
__global__ __launch_bounds__(256) void k_hist(const int* __restrict__ col, int E,
                                              int NBUK, int CH,
                                              int* __restrict__ hist_g) {
    __shared__ int h[256];
    for (int i = threadIdx.x; i < NBUK; i += 256) h[i] = 0;
    __syncthreads();
    int base = blockIdx.x * CH, hi = min(base + CH, E);
    for (int e = base + (int)threadIdx.x; e < hi; e += 256)
        atomicAdd(&h[col[e] >> 9], 1);
    __syncthreads();
    for (int i = threadIdx.x; i < NBUK; i += 256)
        hist_g[blockIdx.x * NBUK + i] = h[i];
}

__global__ __launch_bounds__(256) void k_colscan(const int* __restrict__ hist_g, int NBUK,
                                                 int* __restrict__ histOff,
                                                 int* __restrict__ bucketTotal) {
    __shared__ int s[256];
    const int b = blockIdx.x, t = threadIdx.x;
    int v[4], sum = 0;
#pragma unroll
    for (int j = 0; j < 4; ++j) {
        v[j] = hist_g[(t * 4 + j) * NBUK + b];
        sum += v[j];
    }
    s[t] = sum;
    __syncthreads();
    for (int off = 1; off < 256; off <<= 1) {
        int u = (t >= off) ? s[t - off] : 0;
        __syncthreads();
        s[t] += u;
        __syncthreads();
    }
    int run = s[t] - sum;
#pragma unroll
    for (int j = 0; j < 4; ++j) {
        histOff[b * CHUNKS + t * 4 + j] = run;
        run += v[j];
    }
    if (t == 255) bucketTotal[b] = run;
}

__global__ __launch_bounds__(256) void k_scan_tot(const int* __restrict__ bucketTotal,
                                                  int NBUK, int E, int N,
                                                  int* __restrict__ bucketBase,
                                                  int* __restrict__ row_off) {
    __shared__ int s[256];
    int t = threadIdx.x;
    int v = (t < NBUK) ? bucketTotal[t] : 0;
    s[t] = v;
    __syncthreads();
    for (int off = 1; off < 256; off <<= 1) {
        int u = (t >= off) ? s[t - off] : 0;
        __syncthreads();
        s[t] += u;
        __syncthreads();
    }
    if (t < NBUK) bucketBase[t] = s[t] - v;
    if (t == 0) row_off[N] = E;
}

__global__ __launch_bounds__(256) void k_scatter(const int* __restrict__ row,
                                                 const int* __restrict__ col, int E,
                                                 int NBUK, int CH,
                                                 const int* __restrict__ bucketBase,
                                                 const int* __restrict__ histOff,
                                                 unsigned* __restrict__ ebuf) {
    __shared__ int cur[256];
    for (int i = threadIdx.x; i < NBUK; i += 256)
        cur[i] = bucketBase[i] + histOff[i * CHUNKS + blockIdx.x];
    __syncthreads();
    int base = blockIdx.x * CH, hi = min(base + CH, E);
    for (int e = base + (int)threadIdx.x; e < hi; e += 256) {
        int d = col[e], src = row[e];
        int b = d >> 9;
        int pos = atomicAdd(&cur[b], 1);             // LDS atomic
        ebuf[pos] = ((unsigned)(d & 511) << 17) | (unsigned)src;
    }
}

__global__ __launch_bounds__(512) void k_bucket(const unsigned* __restrict__ ebuf,
                                                const int* __restrict__ bucketBase,
                                                const int* __restrict__ bucketTotal,
                                                int N,
                                                int* __restrict__ row_off,
                                                float* __restrict__ dinv,
                                                int* __restrict__ csr_src) {
    __shared__ int hc[512], of[512];
    const int bid = blockIdx.x, t = threadIdx.x;
    const int base = bucketBase[bid];
    const int cnt  = bucketTotal[bid];
    hc[t] = 0;
    __syncthreads();
    for (int i = t; i < cnt; i += 512)
        atomicAdd(&hc[ebuf[base + i] >> 17], 1);
    __syncthreads();
    int v = hc[t];
    of[t] = v;
    __syncthreads();
    for (int off = 1; off < 512; off <<= 1) {
        int u = (t >= off) ? of[t - off] : 0;
        __syncthreads();
        of[t] += u;
        __syncthreads();
    }
    int excl = of[t] - v;
    int node = bid * 512 + t;
    if (node < N) {
        row_off[node] = base + excl;
        dinv[node] = rsqrtf((float)(v + 1));   // +1 self loop
    }
    of[t] = excl;
    __syncthreads();
    for (int i = t; i < cnt; i += 512) {
        unsigned e = ebuf[base + i];
        int dl = (int)(e >> 17), src = (int)(e & 0x1FFFFu);
        int pos = atomicAdd(&of[dl], 1);       // LDS atomic
        csr_src[base + pos] = src;
    }
}

// ---- MFMA GEMM ------------------------------------------------------------
template <int K, bool BF16IN>
__global__ __launch_bounds__(256) void k_gemm_mfma(const void* __restrict__ xin,
                                                   const float* __restrict__ W,
                                                   const float* __restrict__ dinv,
                                                   unsigned short* __restrict__ out,
                                                   int N) {
    constexpr int KS = K + 8;
    __shared__ short sX[64 * KS];
    __shared__ short sW[64 * KS];
    const int tid = threadIdx.x;
    const int wv = tid >> 6, lane = tid & 63;
    const int q = lane >> 4, m = lane & 15;
    const int nb = blockIdx.x * 64;

    for (int i = tid; i < K * 64; i += 256) {
        int k = i >> 6, c = i & 63;
        sW[c * KS + k] = (short)f2bf(W[i]);
    }
    if (BF16IN) {
        const unsigned short* xb = (const unsigned short*)xin;
        for (int i = tid; i < 64 * (K / 8); i += 256) {
            int r = i / (K / 8), c8 = (i % (K / 8)) * 8;
            int node = nb + r;
            uint4 v = make_uint4(0u, 0u, 0u, 0u);
            if (node < N) v = *(const uint4*)(xb + (size_t)node * K + c8);
            *(uint4*)(&sX[r * KS + c8]) = v;
        }
    } else {
        const float* xf = (const float*)xin;
        for (int i = tid; i < 64 * (K / 8); i += 256) {
            int r = i / (K / 8), c8 = (i % (K / 8)) * 8;
            int node = nb + r;
            uint4 v = make_uint4(0u, 0u, 0u, 0u);
            if (node < N) {
                float4 lo = *(const float4*)(xf + (size_t)node * K + c8);
                float4 hi = *(const float4*)(xf + (size_t)node * K + c8 + 4);
                v.x = packbf(lo.x, lo.y);
                v.y = packbf(lo.z, lo.w);
                v.z = packbf(hi.x, hi.y);
                v.w = packbf(hi.z, hi.w);
            }
            *(uint4*)(&sX[r * KS + c8]) = v;
        }
    }
    __syncthreads();

    f32x4 acc[4] = {};
    const short* aRow = &sX[(wv * 16 + m) * KS + q * 8];
#pragma unroll
    for (int k0 = 0; k0 < K; k0 += 32) {
        bf16x8 a = *(const bf16x8*)(aRow + k0);
#pragma unroll
        for (int ft = 0; ft < 4; ++ft) {
            bf16x8 b = *(const bf16x8*)(&sW[(ft * 16 + m) * KS + k0 + q * 8]);
            acc[ft] = __builtin_amdgcn_mfma_f32_16x16x32_bf16(a, b, acc[ft], 0, 0, 0);
        }
    }
#pragma unroll
    for (int r = 0; r < 4; ++r) {
        int node = nb + wv * 16 + q * 4 + r;
        if (node < N) {
            float di = dinv[node];
#pragma unroll
            for (int ft = 0; ft < 4; ++ft)
                out[(size_t)node * 64 + ft * 16 + m] = f2bf(acc[ft][r] * di);
        }
    }
}

// ---- aggregation: 8 nodes/wave, fold-free, 2-way edge unroll --------------
// slot s = lane>>3 owns node; octet o = lane&7 owns feats [8o,8o+8).
// Two independent prefetch+gather chains per slot (edges it, it+1).
// Self-loop = virtual edge at it==deg; invalid iters clamp to own row + mask.
__global__ __launch_bounds__(256) void k_agg(const unsigned short* __restrict__ xl,
                                             const int* __restrict__ row_off,
                                             const int* __restrict__ csr_src,
                                             const float* __restrict__ dinv,
                                             const float* __restrict__ bias,
                                             unsigned short* __restrict__ out, int N) {
    const int wave = threadIdx.x >> 6, lane = threadIdx.x & 63;
    const int s = lane >> 3, o = lane & 7;
    int node = (blockIdx.x * 4 + wave) * 8 + s;
    const bool active = node < N;
    node = min(node, N - 1);
    const int beg = row_off[node];
    const int deg = row_off[node + 1] - beg;
    const int cnt = active ? deg + 1 : 0;
    int mx = cnt;                         // wave-max over the 8 slots
    mx = max(mx, __shfl_xor(mx, 8, 64));
    mx = max(mx, __shfl_xor(mx, 16, 64));
    mx = max(mx, __shfl_xor(mx, 32, 64));
    const char* xlb = (const char*)xl;
    const unsigned loff = (unsigned)(o << 4);
    f32x2 acc0[4] = {}, acc1[4] = {};
    int idx0 = (0 < deg) ? csr_src[beg] : node;
    int idx1 = (1 < deg) ? csr_src[beg + 1] : node;
    for (int it = 0; it < mx; it += 2) {
        const int c0 = idx0, c1 = idx1;
        const bool v0 = it < cnt, v1 = (it + 1) < cnt;
        idx0 = (it + 2 < deg) ? csr_src[beg + it + 2] : node;  // prefetch
        idx1 = (it + 3 < deg) ? csr_src[beg + it + 3] : node;
        uint4 g0 = *(const uint4*)(xlb + (((unsigned)c0 << 7) | loff));
        uint4 g1 = *(const uint4*)(xlb + (((unsigned)c1 << 7) | loff));
        if (!v0) g0 = make_uint4(0u, 0u, 0u, 0u);
        if (!v1) g1 = make_uint4(0u, 0u, 0u, 0u);
        upadd2(g0, acc0);
        upadd2(g1, acc1);
    }
#pragma unroll
    for (int j = 0; j < 4; ++j) acc0[j] += acc1[j];
    if (active) {
        float di = dinv[node];
        float4 blo = *(const float4*)(bias + o * 8);
        float4 bhi = *(const float4*)(bias + o * 8 + 4);
        uint4 r;
        r.x = packbf(fmaxf(acc0[0].x * di + blo.x, 0.f), fmaxf(acc0[0].y * di + blo.y, 0.f));
        r.y = packbf(fmaxf(acc0[1].x * di + blo.z, 0.f), fmaxf(acc0[1].y * di + blo.w, 0.f));
        r.z = packbf(fmaxf(acc0[2].x * di + bhi.x, 0.f), fmaxf(acc0[2].y * di + bhi.y, 0.f));
        r.w = packbf(fmaxf(acc0[3].x * di + bhi.z, 0.f), fmaxf(acc0[3].y * di + bhi.w, 0.f));
        *(uint4*)(out + (size_t)node * 64 + o * 8) = r;  // 1KB contiguous per wave
    }
}

// Layer-2 agg + final FC + sigmoid (octet fold: shfl_xor 1/2/4 within slot).
__global__ __launch_bounds__(256) void k_agg_fc(const unsigned short* __restrict__ xl,
                                                const int* __restrict__ row_off,
                                                const int* __restrict__ csr_src,
                                                const float* __restrict__ dinv,
                                                const float* __restrict__ bias,
                                                const float* __restrict__ Wfc,
                                                const float* __restrict__ bfc,
                                                float* __restrict__ out, int N) {
    const int wave = threadIdx.x >> 6, lane = threadIdx.x & 63;
    const int s = lane >> 3, o = lane & 7;
    int node = (blockIdx.x * 4 + wave) * 8 + s;
    const bool active = node < N;
    node = min(node, N - 1);
    const int beg = row_off[node];
    const int deg = row_off[node + 1] - beg;
    const int cnt = active ? deg + 1 : 0;
    int mx = cnt;
    mx = max(mx, __shfl_xor(mx, 8, 64));
    mx = max(mx, __shfl_xor(mx, 16, 64));
    mx = max(mx, __shfl_xor(mx, 32, 64));
    const char* xlb = (const char*)xl;
    const unsigned loff = (unsigned)(o << 4);
    f32x2 acc0[4] = {}, acc1[4] = {};
    int idx0 = (0 < deg) ? csr_src[beg] : node;
    int idx1 = (1 < deg) ? csr_src[beg + 1] : node;
    for (int it = 0; it < mx; it += 2) {
        const int c0 = idx0, c1 = idx1;
        const bool v0 = it < cnt, v1 = (it + 1) < cnt;
        idx0 = (it + 2 < deg) ? csr_src[beg + it + 2] : node;
        idx1 = (it + 3 < deg) ? csr_src[beg + it + 3] : node;
        uint4 g0 = *(const uint4*)(xlb + (((unsigned)c0 << 7) | loff));
        uint4 g1 = *(const uint4*)(xlb + (((unsigned)c1 << 7) | loff));
        if (!v0) g0 = make_uint4(0u, 0u, 0u, 0u);
        if (!v1) g1 = make_uint4(0u, 0u, 0u, 0u);
        upadd2(g0, acc0);
        upadd2(g1, acc1);
    }
#pragma unroll
    for (int j = 0; j < 4; ++j) acc0[j] += acc1[j];
    const float di = dinv[node];
    float4 blo = *(const float4*)(bias + o * 8);
    float4 bhi = *(const float4*)(bias + o * 8 + 4);
    float4 wlo = *(const float4*)(Wfc + o * 8);
    float4 whi = *(const float4*)(Wfc + o * 8 + 4);
    float v = 0.f;
    v += fmaxf(acc0[0].x * di + blo.x, 0.f) * wlo.x;
    v += fmaxf(acc0[0].y * di + blo.y, 0.f) * wlo.y;
    v += fmaxf(acc0[1].x * di + blo.z, 0.f) * wlo.z;
    v += fmaxf(acc0[1].y * di + blo.w, 0.f) * wlo.w;
    v += fmaxf(acc0[2].x * di + bhi.x, 0.f) * whi.x;
    v += fmaxf(acc0[2].y * di + bhi.y, 0.f) * whi.y;
    v += fmaxf(acc0[3].x * di + bhi.z, 0.f) * whi.z;
    v += fmaxf(acc0[3].y * di + bhi.w, 0.f) * whi.w;
    v += __shfl_xor(v, 1, 64);
    v += __shfl_xor(v, 2, 64);
    v += __shfl_xor(v, 4, 64);
    if (active && o == 0) out[node] = 1.f / (1.f + expf(-(v + bfc[0])));
}

extern "C" void kernel_launch(void* const* d_in, const int* in_sizes, int n_in,
                              void* d_out, int out_size, void* d_ws, size_t ws_size,
                              hipStream_t stream) {
    const float* x   = (const float*)d_in[0];
    const int*   ei  = (const int*)d_in[1];   // [2, E]: row then col
    const float* W1  = (const float*)d_in[2];
    const float* b1  = (const float*)d_in[3];
    const float* W2  = (const float*)d_in[4];
    const float* b2  = (const float*)d_in[5];
    const float* Wfc = (const float*)d_in[6];
    const float* bfc = (const float*)d_in[7];
    float* out = (float*)d_out;

    const int H = in_sizes[3];          // 64
    const int D = in_sizes[2] / H;      // 128
    const int N = in_sizes[0] / D;      // 100000
    const int E = in_sizes[1] / 2;      // 1600000
    const int* row = ei;
    const int* col = ei + E;
    const int NBUK = (N + 511) >> 9;    // 196 buckets of 512 nodes
    const int CH   = (E + CHUNKS - 1) / CHUNKS;

    // Workspace carve-up (256B aligned slices)
    char* p = (char*)d_ws;
    auto carve = [&](size_t bytes) {
        char* r = p;
        p += (bytes + 255) & ~(size_t)255;
        return (void*)r;
    };
    int*            hist_g      = (int*)carve((size_t)CHUNKS * 256 * 4);
    int*            histOff     = (int*)carve((size_t)256 * CHUNKS * 4);
    int*            bucketTotal = (int*)carve((size_t)256 * 4);
    int*            bucketBase  = (int*)carve((size_t)256 * 4);
    unsigned*       ebuf        = (unsigned*)carve((size_t)E * 4);
    int*            csr_src     = (int*)carve((size_t)E * 4);
    int*            row_off     = (int*)carve((size_t)(N + 1) * 4);
    float*          dinv        = (float*)carve((size_t)N * 4);
    unsigned short* bufXL       = (unsigned short*)carve((size_t)N * 64 * 2);
    unsigned short* bufH        = (unsigned short*)carve((size_t)N * 64 * 2);
    (void)ws_size;

    const int TB = 256;
    // 1. CSR build (bucketed counting sort; no global atomics)
    k_hist<<<CHUNKS, TB, 0, stream>>>(col, E, NBUK, CH, hist_g);
    k_colscan<<<NBUK, TB, 0, stream>>>(hist_g, NBUK, histOff, bucketTotal);
    k_scan_tot<<<1, TB, 0, stream>>>(bucketTotal, NBUK, E, N, bucketBase, row_off);
    k_scatter<<<CHUNKS, TB, 0, stream>>>(row, col, E, NBUK, CH, bucketBase, histOff, ebuf);
    k_bucket<<<NBUK, 512, 0, stream>>>(ebuf, bucketBase, bucketTotal, N,
                                       row_off, dinv, csr_src);

    int gemmGrid = (N + 63) / 64;       // 1563
    int aggGrid  = (N + 31) / 32;       // 3125 (8 nodes/wave x 4 waves)
    // 2. layer 1: xl = bf16((x@W1)*dinv) ; h1 = bf16(relu(dinv*Agg(xl)+b1))
    k_gemm_mfma<128, false><<<gemmGrid, TB, 0, stream>>>(x, W1, dinv, bufXL, N);
    k_agg<<<aggGrid, TB, 0, stream>>>(bufXL, row_off, csr_src, dinv, b1, bufH, N);
    // 3. layer 2: xl2 = bf16((h1@W2)*dinv) ; out = sigmoid(relu(dinv*Agg+b2)@Wfc+bfc)
    k_gemm_mfma<64, true><<<gemmGrid, TB, 0, stream>>>(bufH, W2, dinv, bufXL, N);
    k_agg_fc<<<aggGrid, TB, 0, stream>>>(bufXL, row_off, csr_src, dinv, b2, Wfc, bfc, out, N);
}

// Round 14
// 217.255 us; speedup vs baseline: 1.1313x; 1.0276x over previous
//
#include <hip/hip_runtime.h>
#include <math.h>

// ---------------------------------------------------------------------------
// GCN: h1 = relu(Agg(x@W1)+b1); h2 = relu(Agg(h1@W2)+b2); out = sigmoid(h2@Wfc+bfc)
// Agg(xl)[dst] = dinv[dst] * ( sum_{src->dst} xl_s[src] + xl_s[dst] )
//   where xl_s[n] = (x@W)[n] * dinv[n]   (source-side norm folded into GEMM)
// R2-R9: scan / dinv-fold / counting-sort CSR (no global atomics).
// R10: MFMA GEMMs. R11-R13: fold-free 8-node/wave agg + 2-way gather chains.
// R14a: gemm2 FUSED into k_agg — xl2=dinv*(h1@W2) is row-local, so the wave
//       pushes its 8 h1 rows through LDS + 8 MFMA right after aggregating.
//       Kills bufH round trip (12.8MB w+r) and the gemm2 dispatch.
// R14b: 4-way gather chains in both aggs (4 loads in flight per slot).
// ---------------------------------------------------------------------------

typedef __attribute__((ext_vector_type(8))) short bf16x8;
typedef __attribute__((ext_vector_type(4))) float f32x4;
typedef __attribute__((ext_vector_type(2))) float f32x2;

#define CHUNKS 1024

__device__ __forceinline__ unsigned short f2bf(float f) {
    unsigned u = __float_as_uint(f);
    u += 0x7FFFu + ((u >> 16) & 1u);   // round-to-nearest-even
    return (unsigned short)(u >> 16);
}
__device__ __forceinline__ unsigned packbf(float a, float b) {
    return (unsigned)f2bf(a) | ((unsigned)f2bf(b) << 16);
}
// accumulate 8 bf16 (one uint4) into 4 packed f32x2 accumulators
__device__ __forceinline__ void upadd2(uint4 g, f32x2* a) {
    a[0] += (f32x2){__uint_as_float(g.x << 16), __uint_as_float(g.x & 0xFFFF0000u)};
    a[1] += (f32x2){__uint_as_float(g.y << 16), __uint_as_float(g.y & 0xFFFF0000u)};
    a[2] += (f32x2){__uint_as_float(g.z << 16), __uint_as_float(g.z & 0xFFFF0000u)};
    a[3] += (f32x2){__uint_as_float(g.w << 16), __uint_as_float(g.w & 0xFFFF0000u)};
}

// ---- CSR build: bucketed counting sort (no global atomics) ----------------
__global__ __launch_bounds__(256) void k_hist(const int* __restrict__ col, int E,
                                              int NBUK, int CH,
                                              int* __restrict__ hist_g) {
    __shared__ int h[256];
    for (int i = threadIdx.x; i < NBUK; i += 256) h[i] = 0;
    __syncthreads();
    int base = blockIdx.x * CH, hi = min(base + CH, E);
    for (int e = base + (int)threadIdx.x; e < hi; e += 256)
        atomicAdd(&h[col[e] >> 9], 1);
    __syncthreads();
    for (int i = threadIdx.x; i < NBUK; i += 256)
        hist_g[blockIdx.x * NBUK + i] = h[i];
}

__global__ __launch_bounds__(256) void k_colscan(const int* __restrict__ hist_g, int NBUK,
                                                 int* __restrict__ histOff,
                                                 int* __restrict__ bucketTotal) {
    __shared__ int s[256];
    const int b = blockIdx.x, t = threadIdx.x;
    int v[4], sum = 0;
#pragma unroll
    for (int j = 0; j < 4; ++j) {
        v[j] = hist_g[(t * 4 + j) * NBUK + b];
        sum += v[j];
    }
    s[t] = sum;
    __syncthreads();
    for (int off = 1; off < 256; off <<= 1) {
        int u = (t >= off) ? s[t - off] : 0;
        __syncthreads();
        s[t] += u;
        __syncthreads();
    }
    int run = s[t] - sum;
#pragma unroll
    for (int j = 0; j < 4; ++j) {
        histOff[b * CHUNKS + t * 4 + j] = run;
        run += v[j];
    }
    if (t == 255) bucketTotal[b] = run;
}

__global__ __launch_bounds__(256) void k_scan_tot(const int* __restrict__ bucketTotal,
                                                  int NBUK, int E, int N,
                                                  int* __restrict__ bucketBase,
                                                  int* __restrict__ row_off) {
    __shared__ int s[256];
    int t = threadIdx.x;
    int v = (t < NBUK) ? bucketTotal[t] : 0;
    s[t] = v;
    __syncthreads();
    for (int off = 1; off < 256; off <<= 1) {
        int u = (t >= off) ? s[t - off] : 0;
        __syncthreads();
        s[t] += u;
        __syncthreads();
    }
    if (t < NBUK) bucketBase[t] = s[t] - v;
    if (t == 0) row_off[N] = E;
}

__global__ __launch_bounds__(256) void k_scatter(const int* __restrict__ row,
                                                 const int* __restrict__ col, int E,
                                                 int NBUK, int CH,
                                                 const int* __restrict__ bucketBase,
                                                 const int* __restrict__ histOff,
                                                 unsigned* __restrict__ ebuf) {
    __shared__ int cur[256];
    for (int i = threadIdx.x; i < NBUK; i += 256)
        cur[i] = bucketBase[i] + histOff[i * CHUNKS + blockIdx.x];
    __syncthreads();
    int base = blockIdx.x * CH, hi = min(base + CH, E);
    for (int e = base + (int)threadIdx.x; e < hi; e += 256) {
        int d = col[e], src = row[e];
        int b = d >> 9;
        int pos = atomicAdd(&cur[b], 1);             // LDS atomic
        ebuf[pos] = ((unsigned)(d & 511) << 17) | (unsigned)src;
    }
}

__global__ __launch_bounds__(512) void k_bucket(const unsigned* __restrict__ ebuf,
                                                const int* __restrict__ bucketBase,
                                                const int* __restrict__ bucketTotal,
                                                int N,
                                                int* __restrict__ row_off,
                                                float* __restrict__ dinv,
                                                int* __restrict__ csr_src) {
    __shared__ int hc[512], of[512];
    const int bid = blockIdx.x, t = threadIdx.x;
    const int base = bucketBase[bid];
    const int cnt  = bucketTotal[bid];
    hc[t] = 0;
    __syncthreads();
    for (int i = t; i < cnt; i += 512)
        atomicAdd(&hc[ebuf[base + i] >> 17], 1);
    __syncthreads();
    int v = hc[t];
    of[t] = v;
    __syncthreads();
    for (int off = 1; off < 512; off <<= 1) {
        int u = (t >= off) ? of[t - off] : 0;
        __syncthreads();
        of[t] += u;
        __syncthreads();
    }
    int excl = of[t] - v;
    int node = bid * 512 + t;
    if (node < N) {
        row_off[node] = base + excl;
        dinv[node] = rsqrtf((float)(v + 1));   // +1 self loop
    }
    of[t] = excl;
    __syncthreads();
    for (int i = t; i < cnt; i += 512) {
        unsigned e = ebuf[base + i];
        int dl = (int)(e >> 17), src = (int)(e & 0x1FFFFu);
        int pos = atomicAdd(&of[dl], 1);       // LDS atomic
        csr_src[base + pos] = src;
    }
}

// ---- MFMA GEMM (layer 1 only now) -----------------------------------------
template <int K, bool BF16IN>
__global__ __launch_bounds__(256) void k_gemm_mfma(const void* __restrict__ xin,
                                                   const float* __restrict__ W,
                                                   const float* __restrict__ dinv,
                                                   unsigned short* __restrict__ out,
                                                   int N) {
    constexpr int KS = K + 8;
    __shared__ short sX[64 * KS];
    __shared__ short sW[64 * KS];
    const int tid = threadIdx.x;
    const int wv = tid >> 6, lane = tid & 63;
    const int q = lane >> 4, m = lane & 15;
    const int nb = blockIdx.x * 64;

    for (int i = tid; i < K * 64; i += 256) {
        int k = i >> 6, c = i & 63;
        sW[c * KS + k] = (short)f2bf(W[i]);
    }
    if (BF16IN) {
        const unsigned short* xb = (const unsigned short*)xin;
        for (int i = tid; i < 64 * (K / 8); i += 256) {
            int r = i / (K / 8), c8 = (i % (K / 8)) * 8;
            int node = nb + r;
            uint4 v = make_uint4(0u, 0u, 0u, 0u);
            if (node < N) v = *(const uint4*)(xb + (size_t)node * K + c8);
            *(uint4*)(&sX[r * KS + c8]) = v;
        }
    } else {
        const float* xf = (const float*)xin;
        for (int i = tid; i < 64 * (K / 8); i += 256) {
            int r = i / (K / 8), c8 = (i % (K / 8)) * 8;
            int node = nb + r;
            uint4 v = make_uint4(0u, 0u, 0u, 0u);
            if (node < N) {
                float4 lo = *(const float4*)(xf + (size_t)node * K + c8);
                float4 hi = *(const float4*)(xf + (size_t)node * K + c8 + 4);
                v.x = packbf(lo.x, lo.y);
                v.y = packbf(lo.z, lo.w);
                v.z = packbf(hi.x, hi.y);
                v.w = packbf(hi.z, hi.w);
            }
            *(uint4*)(&sX[r * KS + c8]) = v;
        }
    }
    __syncthreads();

    f32x4 acc[4] = {};
    const short* aRow = &sX[(wv * 16 + m) * KS + q * 8];
#pragma unroll
    for (int k0 = 0; k0 < K; k0 += 32) {
        bf16x8 a = *(const bf16x8*)(aRow + k0);
#pragma unroll
        for (int ft = 0; ft < 4; ++ft) {
            bf16x8 b = *(const bf16x8*)(&sW[(ft * 16 + m) * KS + k0 + q * 8]);
            acc[ft] = __builtin_amdgcn_mfma_f32_16x16x32_bf16(a, b, acc[ft], 0, 0, 0);
        }
    }
#pragma unroll
    for (int r = 0; r < 4; ++r) {
        int node = nb + wv * 16 + q * 4 + r;
        if (node < N) {
            float di = dinv[node];
#pragma unroll
            for (int ft = 0; ft < 4; ++ft)
                out[(size_t)node * 64 + ft * 16 + m] = f2bf(acc[ft][r] * di);
        }
    }
}

// ---- fused layer-1 agg + gemm2 --------------------------------------------
// Phase A (gather): 8 nodes/wave, slot s=lane>>3 owns node, octet o=lane&7
// owns feats [8o,8o+8); 4-way prefetched gather chains; self = virtual edge.
// Phase B (gemm2): wave writes its 8 h1 rows (bf16) into a private LDS
// A-tile (rows 8-15 zero), runs 8 mfma_16x16x32_bf16 vs LDS W2 (same
// verified fragment addressing as k_gemm_mfma), scales by dinv -> xl2.
__global__ __launch_bounds__(256) void k_agg_g2(const unsigned short* __restrict__ xl,
                                                const int* __restrict__ row_off,
                                                const int* __restrict__ csr_src,
                                                const float* __restrict__ dinv,
                                                const float* __restrict__ bias,
                                                const float* __restrict__ W2,
                                                unsigned short* __restrict__ out, int N) {
    constexpr int KS = 72;               // 64 + 8 pad (bf16 elems)
    __shared__ short sH[4 * 16 * KS];    // per-wave 16x64 A-tiles (9KB)
    __shared__ short sW2[64 * KS];       // W2^T bf16 (9KB)
    const int tid = threadIdx.x;
    const int wv = tid >> 6, lane = tid & 63;
    const int s = lane >> 3, o = lane & 7;
    const int q = lane >> 4, m = lane & 15;

    // stage W2 transposed bf16: sW2[n*KS+k] = bf16(W2[k*64+n])
    for (int i = tid; i < 64 * 64; i += 256) {
        int k = i >> 6, n = i & 63;
        sW2[n * KS + k] = (short)f2bf(W2[i]);
    }
    // zero this wave's A-tile rows 8-15 (never written by gather phase)
    short* myH = &sH[wv * 16 * KS];
    for (int i = lane; i < 8 * KS / 4; i += 64)
        ((unsigned long long*)(myH + 8 * KS))[i] = 0ull;
    __syncthreads();                     // sW2 visible to all waves

    const int base8 = (blockIdx.x * 4 + wv) * 8;
    int node = base8 + s;
    const bool active = node < N;
    node = min(node, N - 1);
    const int beg = row_off[node];
    const int deg = row_off[node + 1] - beg;
    const int cnt = active ? deg + 1 : 0;
    int mx = cnt;
    mx = max(mx, __shfl_xor(mx, 8, 64));
    mx = max(mx, __shfl_xor(mx, 16, 64));
    mx = max(mx, __shfl_xor(mx, 32, 64));
    const char* xlb = (const char*)xl;
    const unsigned loff = (unsigned)(o << 4);
    f32x2 acc0[4] = {}, acc1[4] = {};
    int idx[4];
#pragma unroll
    for (int j = 0; j < 4; ++j) idx[j] = (j < deg) ? csr_src[beg + j] : node;
    for (int it = 0; it < mx; it += 4) {
        int c[4];
        bool v[4];
#pragma unroll
        for (int j = 0; j < 4; ++j) {
            c[j] = idx[j];
            v[j] = (it + j) < cnt;
            idx[j] = (it + 4 + j < deg) ? csr_src[beg + it + 4 + j] : node;
        }
        uint4 g0 = *(const uint4*)(xlb + (((unsigned)c[0] << 7) | loff));
        uint4 g1 = *(const uint4*)(xlb + (((unsigned)c[1] << 7) | loff));
        uint4 g2 = *(const uint4*)(xlb + (((unsigned)c[2] << 7) | loff));
        uint4 g3 = *(const uint4*)(xlb + (((unsigned)c[3] << 7) | loff));
        if (!v[0]) g0 = make_uint4(0u, 0u, 0u, 0u);
        if (!v[1]) g1 = make_uint4(0u, 0u, 0u, 0u);
        if (!v[2]) g2 = make_uint4(0u, 0u, 0u, 0u);
        if (!v[3]) g3 = make_uint4(0u, 0u, 0u, 0u);
        upadd2(g0, acc0);
        upadd2(g1, acc1);
        upadd2(g2, acc0);
        upadd2(g3, acc1);
    }
#pragma unroll
    for (int j = 0; j < 4; ++j) acc0[j] += acc1[j];
    // h1 row -> LDS A-tile (bf16), row = slot s
    {
        float di = dinv[node];
        float4 blo = *(const float4*)(bias + o * 8);
        float4 bhi = *(const float4*)(bias + o * 8 + 4);
        uint4 h;
        h.x = packbf(fmaxf(acc0[0].x * di + blo.x, 0.f), fmaxf(acc0[0].y * di + blo.y, 0.f));
        h.y = packbf(fmaxf(acc0[1].x * di + blo.z, 0.f), fmaxf(acc0[1].y * di + blo.w, 0.f));
        h.z = packbf(fmaxf(acc0[2].x * di + bhi.x, 0.f), fmaxf(acc0[2].y * di + bhi.y, 0.f));
        h.w = packbf(fmaxf(acc0[3].x * di + bhi.z, 0.f), fmaxf(acc0[3].y * di + bhi.w, 0.f));
        *(uint4*)(myH + s * KS + o * 8) = h;     // same-wave LDS, no barrier
    }
    // gemm2: 8 MFMA (4 feat-tiles x K=64)
    f32x4 accm[4] = {};
#pragma unroll
    for (int k0 = 0; k0 < 64; k0 += 32) {
        bf16x8 a = *(const bf16x8*)(myH + m * KS + q * 8 + k0);
#pragma unroll
        for (int ft = 0; ft < 4; ++ft) {
            bf16x8 b = *(const bf16x8*)(&sW2[(ft * 16 + m) * KS + k0 + q * 8]);
            accm[ft] = __builtin_amdgcn_mfma_f32_16x16x32_bf16(a, b, accm[ft], 0, 0, 0);
        }
    }
    if (q < 2) {                          // valid rows 0..7
#pragma unroll
        for (int r = 0; r < 4; ++r) {
            int node2 = base8 + q * 4 + r;
            if (node2 < N) {
                float di2 = dinv[node2];
#pragma unroll
                for (int ft = 0; ft < 4; ++ft)
                    out[(size_t)node2 * 64 + ft * 16 + m] = f2bf(accm[ft][r] * di2);
            }
        }
    }
}

// Layer-2 agg + final FC + sigmoid (4-way chains; octet fold shfl 1/2/4).
__global__ __launch_bounds__(256) void k_agg_fc(const unsigned short* __restrict__ xl,
                                                const int* __restrict__ row_off,
                                                const int* __restrict__ csr_src,
                                                const float* __restrict__ dinv,
                                                const float* __restrict__ bias,
                                                const float* __restrict__ Wfc,
                                                const float* __restrict__ bfc,
                                                float* __restrict__ out, int N) {
    const int wave = threadIdx.x >> 6, lane = threadIdx.x & 63;
    const int s = lane >> 3, o = lane & 7;
    int node = (blockIdx.x * 4 + wave) * 8 + s;
    const bool active = node < N;
    node = min(node, N - 1);
    const int beg = row_off[node];
    const int deg = row_off[node + 1] - beg;
    const int cnt = active ? deg + 1 : 0;
    int mx = cnt;
    mx = max(mx, __shfl_xor(mx, 8, 64));
    mx = max(mx, __shfl_xor(mx, 16, 64));
    mx = max(mx, __shfl_xor(mx, 32, 64));
    const char* xlb = (const char*)xl;
    const unsigned loff = (unsigned)(o << 4);
    f32x2 acc0[4] = {}, acc1[4] = {};
    int idx[4];
#pragma unroll
    for (int j = 0; j < 4; ++j) idx[j] = (j < deg) ? csr_src[beg + j] : node;
    for (int it = 0; it < mx; it += 4) {
        int c[4];
        bool v[4];
#pragma unroll
        for (int j = 0; j < 4; ++j) {
            c[j] = idx[j];
            v[j] = (it + j) < cnt;
            idx[j] = (it + 4 + j < deg) ? csr_src[beg + it + 4 + j] : node;
        }
        uint4 g0 = *(const uint4*)(xlb + (((unsigned)c[0] << 7) | loff));
        uint4 g1 = *(const uint4*)(xlb + (((unsigned)c[1] << 7) | loff));
        uint4 g2 = *(const uint4*)(xlb + (((unsigned)c[2] << 7) | loff));
        uint4 g3 = *(const uint4*)(xlb + (((unsigned)c[3] << 7) | loff));
        if (!v[0]) g0 = make_uint4(0u, 0u, 0u, 0u);
        if (!v[1]) g1 = make_uint4(0u, 0u, 0u, 0u);
        if (!v[2]) g2 = make_uint4(0u, 0u, 0u, 0u);
        if (!v[3]) g3 = make_uint4(0u, 0u, 0u, 0u);
        upadd2(g0, acc0);
        upadd2(g1, acc1);
        upadd2(g2, acc0);
        upadd2(g3, acc1);
    }
#pragma unroll
    for (int j = 0; j < 4; ++j) acc0[j] += acc1[j];
    const float di = dinv[node];
    float4 blo = *(const float4*)(bias + o * 8);
    float4 bhi = *(const float4*)(bias + o * 8 + 4);
    float4 wlo = *(const float4*)(Wfc + o * 8);
    float4 whi = *(const float4*)(Wfc + o * 8 + 4);
    float v = 0.f;
    v += fmaxf(acc0[0].x * di + blo.x, 0.f) * wlo.x;
    v += fmaxf(acc0[0].y * di + blo.y, 0.f) * wlo.y;
    v += fmaxf(acc0[1].x * di + blo.z, 0.f) * wlo.z;
    v += fmaxf(acc0[1].y * di + blo.w, 0.f) * wlo.w;
    v += fmaxf(acc0[2].x * di + bhi.x, 0.f) * whi.x;
    v += fmaxf(acc0[2].y * di + bhi.y, 0.f) * whi.y;
    v += fmaxf(acc0[3].x * di + bhi.z, 0.f) * whi.z;
    v += fmaxf(acc0[3].y * di + bhi.w, 0.f) * whi.w;
    v += __shfl_xor(v, 1, 64);
    v += __shfl_xor(v, 2, 64);
    v += __shfl_xor(v, 4, 64);
    if (active && o == 0) out[node] = 1.f / (1.f + expf(-(v + bfc[0])));
}

extern "C" void kernel_launch(void* const* d_in, const int* in_sizes, int n_in,
                              void* d_out, int out_size, void* d_ws, size_t ws_size,
                              hipStream_t stream) {
    const float* x   = (const float*)d_in[0];
    const int*   ei  = (const int*)d_in[1];   // [2, E]: row then col
    const float* W1  = (const float*)d_in[2];
    const float* b1  = (const float*)d_in[3];
    const float* W2  = (const float*)d_in[4];
    const float* b2  = (const float*)d_in[5];
    const float* Wfc = (const float*)d_in[6];
    const float* bfc = (const float*)d_in[7];
    float* out = (float*)d_out;

    const int H = in_sizes[3];          // 64
    const int D = in_sizes[2] / H;      // 128
    const int N = in_sizes[0] / D;      // 100000
    const int E = in_sizes[1] / 2;      // 1600000
    const int* row = ei;
    const int* col = ei + E;
    const int NBUK = (N + 511) >> 9;    // 196 buckets of 512 nodes
    const int CH   = (E + CHUNKS - 1) / CHUNKS;

    // Workspace carve-up (256B aligned slices)
    char* p = (char*)d_ws;
    auto carve = [&](size_t bytes) {
        char* r = p;
        p += (bytes + 255) & ~(size_t)255;
        return (void*)r;
    };
    int*            hist_g      = (int*)carve((size_t)CHUNKS * 256 * 4);
    int*            histOff     = (int*)carve((size_t)256 * CHUNKS * 4);
    int*            bucketTotal = (int*)carve((size_t)256 * 4);
    int*            bucketBase  = (int*)carve((size_t)256 * 4);
    unsigned*       ebuf        = (unsigned*)carve((size_t)E * 4);
    int*            csr_src     = (int*)carve((size_t)E * 4);
    int*            row_off     = (int*)carve((size_t)(N + 1) * 4);
    float*          dinv        = (float*)carve((size_t)N * 4);
    unsigned short* bufXL       = (unsigned short*)carve((size_t)N * 64 * 2);
    unsigned short* bufXL2      = (unsigned short*)carve((size_t)N * 64 * 2);
    (void)ws_size;

    const int TB = 256;
    // 1. CSR build (bucketed counting sort; no global atomics)
    k_hist<<<CHUNKS, TB, 0, stream>>>(col, E, NBUK, CH, hist_g);
    k_colscan<<<NBUK, TB, 0, stream>>>(hist_g, NBUK, histOff, bucketTotal);
    k_scan_tot<<<1, TB, 0, stream>>>(bucketTotal, NBUK, E, N, bucketBase, row_off);
    k_scatter<<<CHUNKS, TB, 0, stream>>>(row, col, E, NBUK, CH, bucketBase, histOff, ebuf);
    k_bucket<<<NBUK, 512, 0, stream>>>(ebuf, bucketBase, bucketTotal, N,
                                       row_off, dinv, csr_src);

    int gemmGrid = (N + 63) / 64;       // 1563
    int aggGrid  = (N + 31) / 32;       // 3125 (8 nodes/wave x 4 waves)
    // 2. layer 1 GEMM: xl = bf16((x@W1)*dinv)
    k_gemm_mfma<128, false><<<gemmGrid, TB, 0, stream>>>(x, W1, dinv, bufXL, N);
    // 3. fused layer-1 agg + gemm2: xl2 = bf16(dinv*(relu(dinv*Agg(xl)+b1)@W2))
    k_agg_g2<<<aggGrid, TB, 0, stream>>>(bufXL, row_off, csr_src, dinv, b1, W2, bufXL2, N);
    // 4. layer-2 agg + FC + sigmoid
    k_agg_fc<<<aggGrid, TB, 0, stream>>>(bufXL2, row_off, csr_src, dinv, b2, Wfc, bfc, out, N);
}